// Round 2
// baseline (77.593 us; speedup 1.0000x reference)
//
#include <hip/hip_runtime.h>

#define SIDE 128
#define PI_F 3.14159265358979f

// out is 4*128*128 = 65536 floats -> 16384 float4 stores = 64 blocks x 256 thr.
__global__ void zero_out(float4* __restrict__ out) {
    out[blockIdx.x * blockDim.x + threadIdx.x] = make_float4(0.f, 0.f, 0.f, 0.f);
}

// One thread per (b, atom, f, row-slot). Gaussian c = pi*4*pi/ff_b >= 2*pi^2,
// so window half-width r <= 1.35 px -> <=3 rows/cols; 4 row-slots cover it.
// 4*2048*5*4 = 163840 threads = 2560 waves = 10 waves/CU (vs 2.5 before).
__global__ void __launch_bounds__(256) potential_scatter(
        const float* __restrict__ coords,
        const float* __restrict__ ff_a,
        const float* __restrict__ ff_b,
        float* __restrict__ out,
        int B, int A) {
    int tid = blockIdx.x * blockDim.x + threadIdx.x;
    int total = B * A * 5 * 4;
    if (tid >= total) return;
    int r_slot = tid & 3;
    int rest   = tid >> 2;
    int f  = rest % 5;
    int ba = rest / 5;
    int a  = ba % A;
    int b  = ba / A;

    float x  = coords[(size_t)(b * A + a) * 3 + 0];
    float y  = coords[(size_t)(b * A + a) * 3 + 1];
    float fa = ff_a[a * 5 + f];
    float fb = ff_b[a * 5 + f];

    float invb = (4.0f * PI_F) / fb;
    float coef = fa * invb;          // peak amplitude in [~3.1, ~50.3]
    float c    = PI_F * invb;        // exponent scale in [~19.7, ~79]

    float cx = x + 64.0f;            // pixel-space center (column)
    float cy = y + 64.0f;            // pixel-space center (row)

    // keep pixels where coef*exp(-c*d2) > ~1e-14  <=>  c*d2 < ln(coef)+32
    float r2 = (__logf(coef) + 32.0f) / c;
    float r  = sqrtf(r2);

    int j0 = max(0, (int)ceilf(cx - r));
    int j1 = min(SIDE - 1, (int)floorf(cx + r));
    int i0 = max(0, (int)ceilf(cy - r));
    int i1 = min(SIDE - 1, (int)floorf(cy + r));

    int i = i0 + r_slot;             // this thread's row
    if (j1 < j0 || i > i1) return;   // off-grid blob or unused row slot

    float dy = (float)i - cy;
    float wy = coef * __expf(-c * dy * dy);

    float* rowp = out + (size_t)b * (SIDE * SIDE) + i * SIDE;
    for (int j = j0; j <= j1; ++j) { // <= 3 iterations
        float dx = (float)j - cx;
        atomicAdd(&rowp[j], wy * __expf(-c * dx * dx));
    }
}

extern "C" void kernel_launch(void* const* d_in, const int* in_sizes, int n_in,
                              void* d_out, int out_size, void* d_ws, size_t ws_size,
                              hipStream_t stream) {
    const float* coords = (const float*)d_in[0];
    const float* ffa    = (const float*)d_in[1];
    const float* ffb    = (const float*)d_in[2];
    float* out = (float*)d_out;

    int A = in_sizes[1] / 5;          // 2048
    int B = in_sizes[0] / (A * 3);    // 4

    // Custom zero kernel: the rocclr fillBuffer path costs ~40 us for 256 KB.
    // 65536 floats = 16384 float4 -> exactly 64 blocks x 256 threads.
    zero_out<<<(out_size / 4 + 255) / 256, 256, 0, stream>>>((float4*)out);

    int total = B * A * 5 * 4;        // 163840 threads (4 row-slots per blob)
    int block = 256;
    int grid  = (total + block - 1) / block;
    potential_scatter<<<grid, block, 0, stream>>>(coords, ffa, ffb, out, B, A);
}